// Round 8
// baseline (827.837 us; speedup 1.0000x reference)
//
#include <hip/hip_runtime.h>
#include <hip/hip_cooperative_groups.h>
#include <math.h>

namespace cg = cooperative_groups;

#define DD 128
#define G 16
#define TPB 512
#define SMAX 2048
#define NBLK_MAX 256

__device__ __forceinline__ float sigmoidf(float x) { return 1.0f / (1.0f + expf(-x)); }

// ---------------------------------------------------------------------------
// R13 = R12 with Phase D coverage bug fixed.
// R12 bug: Phase D splits k-tiles across two waves (dq halves) but rotated
// each half by that wave's OWN b0 -> union of {b0_w0+0..15} and {b0_w1+16..31}
// (mod 32) has gaps/double-counts when b0 differs -> absmax 0.43.
// Fix: rotate WITHIN the half: kk = s0 + ((i + b0) & 15). Coverage exact.
// Everything else identical to R12 (G=16, per-wave stagger, 2-deep weight
// prefetch, all-512-thread Phase D).
// ---------------------------------------------------------------------------
struct PParams {
  const int* heads; const int* tails; const float* times;
  float* node_rep; float* cell_head; float* hidden_head; float* cell_tail; float* hidden_tail;
  const float* beh; const float* bet; const float* bh; const float* bt;
  const float* bdh; const float* bdt;
  const float* Wsrc[12];   // Weh1,Weh2,Wet1,Wet2,Wdh,Wdt,Wc1,Wc2,Wxh,Whh,Wxt,Wht
  float* Wt[12];           // k4-tiled: Wt[m][(k4*E+e)*4+j] = W[4k4+j][e]
  float* out; float* rt;
  int* order; int* level_off; int* n_levels; int* ph; int* pt;
  int S;
};

// read 16 consecutive floats (one 16-g row) from plane oo at row dd
#define RDP(x0,x1,x2,x3, oo, dd) { const int _b=(oo)+(dd)*16; \
  x0=*(const float4*)&S_[_b];   x1=*(const float4*)&S_[_b+4]; \
  x2=*(const float4*)&S_[_b+8]; x3=*(const float4*)&S_[_b+12]; }

#define FMA16_2(wa,wb, x0,x1,x2,x3, y0,y1,y2,y3) { \
  a[0]+=x0.x*(wa)+y0.x*(wb);  a[1]+=x0.y*(wa)+y0.y*(wb); \
  a[2]+=x0.z*(wa)+y0.z*(wb);  a[3]+=x0.w*(wa)+y0.w*(wb); \
  a[4]+=x1.x*(wa)+y1.x*(wb);  a[5]+=x1.y*(wa)+y1.y*(wb); \
  a[6]+=x1.z*(wa)+y1.z*(wb);  a[7]+=x1.w*(wa)+y1.w*(wb); \
  a[8]+=x2.x*(wa)+y2.x*(wb);  a[9]+=x2.y*(wa)+y2.y*(wb); \
  a[10]+=x2.z*(wa)+y2.z*(wb); a[11]+=x2.w*(wa)+y2.w*(wb); \
  a[12]+=x3.x*(wa)+y3.x*(wb); a[13]+=x3.y*(wa)+y3.y*(wb); \
  a[14]+=x3.z*(wa)+y3.z*(wb); a[15]+=x3.w*(wa)+y3.w*(wb); }

#define FMA16_1(wa, x0,x1,x2,x3) { \
  a[0]+=x0.x*(wa);  a[1]+=x0.y*(wa);  a[2]+=x0.z*(wa);  a[3]+=x0.w*(wa); \
  a[4]+=x1.x*(wa);  a[5]+=x1.y*(wa);  a[6]+=x1.z*(wa);  a[7]+=x1.w*(wa); \
  a[8]+=x2.x*(wa);  a[9]+=x2.y*(wa);  a[10]+=x2.z*(wa); a[11]+=x2.w*(wa); \
  a[12]+=x3.x*(wa); a[13]+=x3.y*(wa); a[14]+=x3.z*(wa); a[15]+=x3.w*(wa); }

#define STEP2(oo1,oo2, dd, wa, wb) { float4 _x0,_x1,_x2,_x3,_y0,_y1,_y2,_y3; \
  RDP(_x0,_x1,_x2,_x3, oo1, dd); RDP(_y0,_y1,_y2,_y3, oo2, dd); \
  FMA16_2(wa,wb,_x0,_x1,_x2,_x3,_y0,_y1,_y2,_y3); }

#define STEP1(oo, dd, wa) { float4 _x0,_x1,_x2,_x3; \
  RDP(_x0,_x1,_x2,_x3, oo, dd); FMA16_1(wa,_x0,_x1,_x2,_x3); }

#define K4STEP2(oo1,oo2, kk, wv1, wv2) { const int _d4=(kk)*4; \
  STEP2(oo1,oo2,_d4+0,(wv1).x,(wv2).x); STEP2(oo1,oo2,_d4+1,(wv1).y,(wv2).y); \
  STEP2(oo1,oo2,_d4+2,(wv1).z,(wv2).z); STEP2(oo1,oo2,_d4+3,(wv1).w,(wv2).w); }

#define K4STEP1(oo, kk, wv) { const int _d4=(kk)*4; \
  STEP1(oo,_d4+0,(wv).x); STEP1(oo,_d4+1,(wv).y); \
  STEP1(oo,_d4+2,(wv).z); STEP1(oo,_d4+3,(wv).w); }

#define BSTEP(dd, c1,c2,c3,c4) { \
  float4 _e0,_e1,_e2,_e3,_h0,_h1,_h2,_h3,_f0,_f1,_f2,_f3,_q0,_q1,_q2,_q3; \
  RDP(_e0,_e1,_e2,_e3, O_EH, dd);  RDP(_h0,_h1,_h2,_h3, O_HHS, dd); \
  RDP(_f0,_f1,_f2,_f3, O_ET, dd);  RDP(_q0,_q1,_q2,_q3, O_HTS, dd); \
  zh[0]+=_e0.x*(c1)+_h0.x*(c2);  zh[1]+=_e0.y*(c1)+_h0.y*(c2); \
  zh[2]+=_e0.z*(c1)+_h0.z*(c2);  zh[3]+=_e0.w*(c1)+_h0.w*(c2); \
  zh[4]+=_e1.x*(c1)+_h1.x*(c2);  zh[5]+=_e1.y*(c1)+_h1.y*(c2); \
  zh[6]+=_e1.z*(c1)+_h1.z*(c2);  zh[7]+=_e1.w*(c1)+_h1.w*(c2); \
  zh[8]+=_e2.x*(c1)+_h2.x*(c2);  zh[9]+=_e2.y*(c1)+_h2.y*(c2); \
  zh[10]+=_e2.z*(c1)+_h2.z*(c2); zh[11]+=_e2.w*(c1)+_h2.w*(c2); \
  zh[12]+=_e3.x*(c1)+_h3.x*(c2); zh[13]+=_e3.y*(c1)+_h3.y*(c2); \
  zh[14]+=_e3.z*(c1)+_h3.z*(c2); zh[15]+=_e3.w*(c1)+_h3.w*(c2); \
  zt[0]+=_f0.x*(c3)+_q0.x*(c4);  zt[1]+=_f0.y*(c3)+_q0.y*(c4); \
  zt[2]+=_f0.z*(c3)+_q0.z*(c4);  zt[3]+=_f0.w*(c3)+_q0.w*(c4); \
  zt[4]+=_f1.x*(c3)+_q1.x*(c4);  zt[5]+=_f1.y*(c3)+_q1.y*(c4); \
  zt[6]+=_f1.z*(c3)+_q1.z*(c4);  zt[7]+=_f1.w*(c3)+_q1.w*(c4); \
  zt[8]+=_f2.x*(c3)+_q2.x*(c4);  zt[9]+=_f2.y*(c3)+_q2.y*(c4); \
  zt[10]+=_f2.z*(c3)+_q2.z*(c4); zt[11]+=_f2.w*(c3)+_q2.w*(c4); \
  zt[12]+=_f3.x*(c3)+_q3.x*(c4); zt[13]+=_f3.y*(c3)+_q3.y*(c4); \
  zt[14]+=_f3.z*(c3)+_q3.z*(c4); zt[15]+=_f3.w*(c3)+_q3.w*(c4); }

#define K4B(kk, wx1,wh1,wx2,wh2) { const int _d4=(kk)*4; \
  BSTEP(_d4+0,(wx1).x,(wh1).x,(wx2).x,(wh2).x); \
  BSTEP(_d4+1,(wx1).y,(wh1).y,(wx2).y,(wh2).y); \
  BSTEP(_d4+2,(wx1).z,(wh1).z,(wx2).z,(wh2).z); \
  BSTEP(_d4+3,(wx1).w,(wh1).w,(wx2).w,(wh2).w); }

#define LDW(W,kk)  (*(const float4*)&(W)[(((kk)*128)+e)*4])
#define LDWB(W,kk) (*(const float4*)&(W)[((size_t)((kk)*512+c))*4])

__global__ __launch_bounds__(TPB, 2) void process_kernel(PParams p) {
  cg::grid_group grid = cg::this_grid();
  const int tid = threadIdx.x;
  const int bid = (int)blockIdx.x;
  const int nb  = (int)gridDim.x;
  const int Sn  = p.S;
  const int b0  = ((bid * 8 + (tid >> 6)) * 7) & 31;   // per-WAVE k4 stagger

  __shared__ __align__(16) float S_[32768];   // 128 KB
  __shared__ int sIdx[G], hIdx[G], tIdx[G];
  __shared__ float tmv[G], decHs[G], decTs[G];
  __shared__ int sh_changed, sh_maxl;

  // plane offsets (floats), stride 16 per d-row
  const int O_REPH = 0,     O_REPT = 2048,  O_CHS = 4096,  O_CTS = 6144;  // dead after A
  const int O_ZH   = 0,     O_ZT   = 8192;                                 // born in B (overlay)
  const int O_HHS  = 16384, O_HTS  = 18432, O_HTH = 20480, O_HHT = 22528;  // persistent
  const int O_EH   = 24576, O_ET   = 26624;                                // edge (A..B) == nh (C..D)
  const int O_CAH  = 28672, O_CAT  = 30720;                                // cadj (A..C), D-partial scratch

  // ---- pred: wave-per-j
  {
    const int wv = tid >> 6, lane = tid & 63;
    for (int j = bid * 8 + wv; j < Sn; j += nb * 8) {
      const int myh = p.heads[j], myt = p.tails[j];
      int mph = -1, mpt = -1;
      for (int i = lane; i < j; i += 64) {
        int a = p.heads[i], b = p.tails[i];
        if (a == myh || b == myh) mph = i;
        if (a == myt || b == myt) mpt = i;
      }
#pragma unroll
      for (int off = 32; off > 0; off >>= 1) {
        mph = max(mph, __shfl_down(mph, off));
        mpt = max(mpt, __shfl_down(mpt, off));
      }
      if (lane == 0) { p.ph[j] = mph; p.pt[j] = mpt; }
    }
  }

  // ---- weight transpose into k4 layout
  {
    for (int i = bid * TPB + tid; i < 98304; i += nb * TPB) {
      int mat, k4, e, E;
      if (i < 32768) {
        mat = i >> 12; int rem = i & 4095; k4 = rem >> 7; e = rem & 127; E = 128;
      } else {
        int i2 = i - 32768; mat = 8 + (i2 >> 14); int rem = i2 & 16383;
        k4 = rem >> 9; e = rem & 511; E = 512;
      }
      const float* Wm = p.Wsrc[mat];
      float4 v;
      v.x = Wm[(4 * k4 + 0) * E + e];
      v.y = Wm[(4 * k4 + 1) * E + e];
      v.z = Wm[(4 * k4 + 2) * E + e];
      v.w = Wm[(4 * k4 + 3) * E + e];
      *(float4*)&p.Wt[mat][(size_t)(k4 * E + e) * 4] = v;
    }
  }
  __threadfence();
  grid.sync();

  // ---- level finalize (block 0; S_ as int scratch)
  if (bid == 0) {
    int* lvl = (int*)S_;
    int* ph2 = lvl + SMAX;
    int* pt2 = ph2 + SMAX;
    int* cnt = pt2 + SMAX;
    for (int j = tid; j < Sn; j += TPB) { ph2[j] = p.ph[j]; pt2[j] = p.pt[j]; lvl[j] = 1; }
    __syncthreads();
    for (int it = 0; it < Sn + 2; ++it) {
      if (tid == 0) sh_changed = 0;
      __syncthreads();
      for (int j = tid; j < Sn; j += TPB) {
        int l = 1;
        int a = ph2[j]; if (a >= 0) l = lvl[a] + 1;
        int b = pt2[j]; if (b >= 0) { int lb = lvl[b] + 1; if (lb > l) l = lb; }
        if (l != lvl[j]) { lvl[j] = l; sh_changed = 1; }
      }
      __syncthreads();
      if (!sh_changed) break;
      __syncthreads();
    }
    if (tid == 0) sh_maxl = 0;
    __syncthreads();
    for (int j = tid; j < Sn; j += TPB) atomicMax(&sh_maxl, lvl[j]);
    __syncthreads();
    const int Mlvl = sh_maxl;
    for (int l = tid; l < Mlvl; l += TPB) cnt[l] = 0;
    __syncthreads();
    for (int j = tid; j < Sn; j += TPB) atomicAdd(&cnt[lvl[j] - 1], 1);
    __syncthreads();
    if (tid == 0) {
      int run = 0; p.level_off[0] = 0;
      for (int l = 0; l < Mlvl; ++l) { run += cnt[l]; p.level_off[l + 1] = run; }
      p.n_levels[0] = Mlvl;
    }
    __syncthreads();
    for (int l = tid; l < Mlvl; l += TPB) cnt[l] = 0;
    __syncthreads();
    for (int j = tid; j < Sn; j += TPB) {
      int lv2 = lvl[j] - 1;
      int pos = p.level_off[lv2] + atomicAdd(&cnt[lv2], 1);
      p.order[pos] = j;
    }
  }
  __threadfence();
  grid.sync();

  int nlv = p.n_levels[0];
  if (nlv < 0) nlv = 0;
  if (nlv > SMAX) nlv = SMAX;

  for (int lv = 0; lv < nlv; ++lv) {
    const int beg = p.level_off[lv], end = p.level_off[lv + 1];

    for (int base = beg + bid * G; base < end; base += nb * G) {
      const int ng = min(G, end - base);
      __syncthreads();
      if (tid < ng) {
        int s = p.order[base + tid]; sIdx[tid] = s;
        int h = p.heads[s], t = p.tails[s];
        hIdx[tid] = h; tIdx[tid] = t;
        float tm = p.times[s]; tmv[tid] = tm;
        decHs[tid] = expf(-(tm - p.rt[h]));
        decTs[tid] = expf(-(tm - p.rt[t]));
      }
      __syncthreads();

      // -------- Gather: node rows into [d][16] LDS + emit outputs
      {
        const int d = tid & 127;
        for (int g = tid >> 7; g < ng; g += 4) {
          const size_t oh = (size_t)hIdx[g] * DD + d;
          const size_t ot = (size_t)tIdx[g] * DD + d;
          const int b = d * 16 + g;
          float rh = p.node_rep[oh];
          S_[O_REPH + b] = rh; p.out[(size_t)sIdx[g] * DD + d] = rh;
          S_[O_CHS + b] = p.cell_head[oh];
          S_[O_HHS + b] = p.hidden_head[oh];
          S_[O_HTH + b] = p.hidden_tail[oh];
          float rt_ = p.node_rep[ot];
          S_[O_REPT + b] = rt_; p.out[(size_t)(Sn + sIdx[g]) * DD + d] = rt_;
          S_[O_CTS + b] = p.cell_tail[ot];
          S_[O_HTS + b] = p.hidden_tail[ot];
          S_[O_HHT + b] = p.hidden_head[ot];
        }
      }
      __syncthreads();

      // -------- Phase A: edges (roles 0,1) + decayed cell adjust (roles 2,3)
      {
        const int role = tid >> 7, e = tid & 127;
        if (role <= 1) {
          const float* W1 = p.Wt[role ? 2 : 0];
          const float* W2 = p.Wt[role ? 3 : 1];
          float bv = role ? p.bet[e] : p.beh[e];
          float a[16];
#pragma unroll
          for (int g = 0; g < 16; ++g) a[g] = bv;
          float4 wA1 = LDW(W1, b0), wA2 = LDW(W2, b0);
          const int kB0 = (b0 + 1) & 31;
          float4 wB1 = LDW(W1, kB0), wB2 = LDW(W2, kB0);
          for (int k4 = 0; k4 < 32; k4 += 2) {
            const int kp1 = (k4 + 2 + b0) & 31, kp2 = (k4 + 3 + b0) & 31;
            float4 nA1 = LDW(W1, kp1), nA2 = LDW(W2, kp1);
            float4 nB1 = LDW(W1, kp2), nB2 = LDW(W2, kp2);
            const int kkA = (k4 + b0) & 31, kkB = (k4 + 1 + b0) & 31;
            K4STEP2(O_REPH, O_REPT, kkA, wA1, wA2);
            K4STEP2(O_REPH, O_REPT, kkB, wB1, wB2);
            wA1 = nA1; wA2 = nA2; wB1 = nB1; wB2 = nB2;
          }
          const int dst = role ? O_ET : O_EH;
          *(float4*)&S_[dst + e*16 + 0]  = make_float4(tanhf(a[0]),  tanhf(a[1]),  tanhf(a[2]),  tanhf(a[3]));
          *(float4*)&S_[dst + e*16 + 4]  = make_float4(tanhf(a[4]),  tanhf(a[5]),  tanhf(a[6]),  tanhf(a[7]));
          *(float4*)&S_[dst + e*16 + 8]  = make_float4(tanhf(a[8]),  tanhf(a[9]),  tanhf(a[10]), tanhf(a[11]));
          *(float4*)&S_[dst + e*16 + 12] = make_float4(tanhf(a[12]), tanhf(a[13]), tanhf(a[14]), tanhf(a[15]));
        } else {
          const int th = (role == 2);
          const float* W = p.Wt[th ? 4 : 5];
          const int co = th ? O_CHS : O_CTS;
          float bv = th ? p.bdh[e] : p.bdt[e];
          const float* decA = th ? decHs : decTs;
          float a[16];
#pragma unroll
          for (int g = 0; g < 16; ++g) a[g] = bv;
          float4 wA = LDW(W, b0);
          float4 wB = LDW(W, (b0 + 1) & 31);
          for (int k4 = 0; k4 < 32; k4 += 2) {
            const int kp1 = (k4 + 2 + b0) & 31, kp2 = (k4 + 3 + b0) & 31;
            float4 nA = LDW(W, kp1);
            float4 nB = LDW(W, kp2);
            const int kkA = (k4 + b0) & 31, kkB = (k4 + 1 + b0) & 31;
            K4STEP1(co, kkA, wA);
            K4STEP1(co, kkB, wB);
            wA = nA; wB = nB;
          }
          float4 c0, c1, c2, c3;
          RDP(c0, c1, c2, c3, co, e);     // c-row for this e (stride 16)
          const int dst = th ? O_CAH : O_CAT;
          float cs;
          float4 o;
          cs = tanhf(a[0]);  o.x = c0.x - cs + cs * decA[0];
          cs = tanhf(a[1]);  o.y = c0.y - cs + cs * decA[1];
          cs = tanhf(a[2]);  o.z = c0.z - cs + cs * decA[2];
          cs = tanhf(a[3]);  o.w = c0.w - cs + cs * decA[3];
          *(float4*)&S_[dst + e*16 + 0] = o;
          cs = tanhf(a[4]);  o.x = c1.x - cs + cs * decA[4];
          cs = tanhf(a[5]);  o.y = c1.y - cs + cs * decA[5];
          cs = tanhf(a[6]);  o.z = c1.z - cs + cs * decA[6];
          cs = tanhf(a[7]);  o.w = c1.w - cs + cs * decA[7];
          *(float4*)&S_[dst + e*16 + 4] = o;
          cs = tanhf(a[8]);  o.x = c2.x - cs + cs * decA[8];
          cs = tanhf(a[9]);  o.y = c2.y - cs + cs * decA[9];
          cs = tanhf(a[10]); o.z = c2.z - cs + cs * decA[10];
          cs = tanhf(a[11]); o.w = c2.w - cs + cs * decA[11];
          *(float4*)&S_[dst + e*16 + 8] = o;
          cs = tanhf(a[12]); o.x = c3.x - cs + cs * decA[12];
          cs = tanhf(a[13]); o.y = c3.y - cs + cs * decA[13];
          cs = tanhf(a[14]); o.z = c3.z - cs + cs * decA[14];
          cs = tanhf(a[15]); o.w = c3.w - cs + cs * decA[15];
          *(float4*)&S_[dst + e*16 + 12] = o;
        }
      }
      __syncthreads();

      // -------- Phase B: z = x@Wx + h@Wh + b, both sides, col/thread, 32 accs
      {
        const int c = tid;
        const float* TXh = p.Wt[8];  const float* THh = p.Wt[9];
        const float* TXt = p.Wt[10]; const float* THt = p.Wt[11];
        float zh[16], zt[16];
        float bhv = p.bh[c], btv = p.bt[c];
#pragma unroll
        for (int g = 0; g < 16; ++g) { zh[g] = bhv; zt[g] = btv; }
        float4 wxh = LDWB(TXh, b0), whh = LDWB(THh, b0);
        float4 wxt = LDWB(TXt, b0), wht = LDWB(THt, b0);
        for (int k4 = 0; k4 < 32; ++k4) {
          const int kkn = (k4 + 1 + b0) & 31;
          float4 nxh = LDWB(TXh, kkn), nhh = LDWB(THh, kkn);
          float4 nxt = LDWB(TXt, kkn), nht = LDWB(THt, kkn);
          const int kk = (k4 + b0) & 31;
          K4B(kk, wxh, whh, wxt, wht);
          wxh = nxh; whh = nhh; wxt = nxt; wht = nht;
        }
        // ZH/ZT overlay gather planes (dead since A's entry sync)
        *(float4*)&S_[O_ZH + c*16 + 0]  = make_float4(zh[0],  zh[1],  zh[2],  zh[3]);
        *(float4*)&S_[O_ZH + c*16 + 4]  = make_float4(zh[4],  zh[5],  zh[6],  zh[7]);
        *(float4*)&S_[O_ZH + c*16 + 8]  = make_float4(zh[8],  zh[9],  zh[10], zh[11]);
        *(float4*)&S_[O_ZH + c*16 + 12] = make_float4(zh[12], zh[13], zh[14], zh[15]);
        *(float4*)&S_[O_ZT + c*16 + 0]  = make_float4(zt[0],  zt[1],  zt[2],  zt[3]);
        *(float4*)&S_[O_ZT + c*16 + 4]  = make_float4(zt[4],  zt[5],  zt[6],  zt[7]);
        *(float4*)&S_[O_ZT + c*16 + 8]  = make_float4(zt[8],  zt[9],  zt[10], zt[11]);
        *(float4*)&S_[O_ZT + c*16 + 12] = make_float4(zt[12], zt[13], zt[14], zt[15]);
      }
      __syncthreads();

      // -------- Phase C: gates, c/h update, scatter state, rt update
      {
        const int side = tid >> 8, sub = (tid >> 7) & 1, e2 = tid & 127;
        const int zo = side ? O_ZT : O_ZH;
        const int co = side ? O_CAT : O_CAH;
        const int no = side ? O_ET : O_EH;
        float* ctab = side ? p.cell_tail : p.cell_head;
        float* htab = side ? p.hidden_tail : p.hidden_head;
        for (int q = 0; q < 8; ++q) {
          int g = sub + 2 * q;
          if (g >= ng) continue;
          float iv = sigmoidf(S_[zo + e2 * 16 + g]);
          float fv = sigmoidf(S_[zo + (128 + e2) * 16 + g]);
          float ov = sigmoidf(S_[zo + (256 + e2) * 16 + g]);
          float gv = tanhf(S_[zo + (384 + e2) * 16 + g]);
          float cadj = S_[co + e2 * 16 + g];
          float cn = fv * cadj + iv * gv;
          float hn = ov * tanhf(cn);
          S_[no + e2 * 16 + g] = hn;
          int node = side ? tIdx[g] : hIdx[g];
          ctab[(size_t)node * DD + e2] = cn;
          htab[(size_t)node * DD + e2] = hn;
        }
        if (tid < 2 * G) {
          int g = tid & (G - 1);
          if (g < ng) p.rt[(tid >= G) ? tIdx[g] : hIdx[g]] = tmv[g];
        }
      }
      __syncthreads();

      // -------- Phase D: combiner (all 512 threads; d-halves + LDS combine)
      {
        const int role = tid >> 8;          // 0: head output, 1: tail output
        const int dq = (tid >> 7) & 1;      // d-half
        const int e = tid & 127;
        const int xo = role ? O_HHT : O_EH;   // @ Wc1
        const int yo = role ? O_ET  : O_HTH;  // @ Wc2
        const float* W1 = p.Wt[6];
        const float* W2 = p.Wt[7];
        float a[16];
#pragma unroll
        for (int g = 0; g < 16; ++g) a[g] = 0.0f;
        const int s0 = dq * 16;
        // R13 FIX: rotate WITHIN the 16-tile half so dq=0 covers exactly
        // {0..15} and dq=1 exactly {16..31} regardless of per-wave b0.
        const int k0 = s0 + (b0 & 15), k1 = s0 + ((b0 + 1) & 15);
        float4 wA1 = LDW(W1, k0), wA2 = LDW(W2, k0);
        float4 wB1 = LDW(W1, k1), wB2 = LDW(W2, k1);
        for (int i = 0; i < 16; i += 2) {
          const int kp1 = s0 + ((i + 2 + b0) & 15), kp2 = s0 + ((i + 3 + b0) & 15);
          float4 nA1 = LDW(W1, kp1), nA2 = LDW(W2, kp1);
          float4 nB1 = LDW(W1, kp2), nB2 = LDW(W2, kp2);
          const int kkA = s0 + ((i + b0) & 15), kkB = s0 + ((i + 1 + b0) & 15);
          K4STEP2(xo, yo, kkA, wA1, wA2);
          K4STEP2(xo, yo, kkB, wB1, wB2);
          wA1 = nA1; wA2 = nA2; wB1 = nB1; wB2 = nB2;
        }
        const int scr = role ? O_CAT : O_CAH;   // cadj dead after Phase C
        if (dq == 1) {
          *(float4*)&S_[scr + e*16 + 0]  = make_float4(a[0],  a[1],  a[2],  a[3]);
          *(float4*)&S_[scr + e*16 + 4]  = make_float4(a[4],  a[5],  a[6],  a[7]);
          *(float4*)&S_[scr + e*16 + 8]  = make_float4(a[8],  a[9],  a[10], a[11]);
          *(float4*)&S_[scr + e*16 + 12] = make_float4(a[12], a[13], a[14], a[15]);
        }
        __syncthreads();
        if (dq == 0) {
          float4 p0 = *(const float4*)&S_[scr + e*16 + 0];
          float4 p1 = *(const float4*)&S_[scr + e*16 + 4];
          float4 p2 = *(const float4*)&S_[scr + e*16 + 8];
          float4 p3 = *(const float4*)&S_[scr + e*16 + 12];
          a[0] += p0.x;  a[1] += p0.y;  a[2] += p0.z;  a[3] += p0.w;
          a[4] += p1.x;  a[5] += p1.y;  a[6] += p1.z;  a[7] += p1.w;
          a[8] += p2.x;  a[9] += p2.y;  a[10] += p2.z; a[11] += p2.w;
          a[12] += p3.x; a[13] += p3.y; a[14] += p3.z; a[15] += p3.w;
#pragma unroll
          for (int g = 0; g < 16; ++g) {
            if (g < ng) {
              if (role == 0) {
                if (hIdx[g] != tIdx[g])
                  p.node_rep[(size_t)hIdx[g] * DD + e] = tanhf(a[g]);
              } else {
                p.node_rep[(size_t)tIdx[g] * DD + e] = tanhf(a[g]);
              }
            }
          }
        }
      }
    }
    __threadfence();
    grid.sync();
  }
}

// ---------------------------------------------------------------------------
extern "C" void kernel_launch(void* const* d_in, const int* in_sizes, int n_in,
                              void* d_out, int out_size, void* d_ws, size_t ws_size,
                              hipStream_t stream) {
  const int* heads = (const int*)d_in[0];
  const int* tails = (const int*)d_in[1];
  const float* times = (const float*)d_in[2];
  float* node_rep    = (float*)d_in[3];
  float* cell_head   = (float*)d_in[4];
  float* hidden_head = (float*)d_in[5];
  float* cell_tail   = (float*)d_in[6];
  float* hidden_tail = (float*)d_in[7];

  const int S = in_sizes[0];
  const int N = in_sizes[3] / DD;

  char* ws = (char*)d_ws;
  size_t off = 0;
  float* rt = (float*)ws;
  off = (((size_t)N * 4) + 511) & ~(size_t)511;
  int* order     = (int*)(ws + off); off += (size_t)SMAX * 4;
  int* level_off = (int*)(ws + off); off += (size_t)(SMAX + 1) * 4;
  int* n_levels  = (int*)(ws + off); off += 64 * 4;
  int* ph        = (int*)(ws + off); off += (size_t)SMAX * 4;
  int* pt        = (int*)(ws + off); off += (size_t)SMAX * 4;
  off = (off + 255) & ~(size_t)255;

  PParams p;
  p.heads = heads; p.tails = tails; p.times = times;
  p.node_rep = node_rep; p.cell_head = cell_head; p.hidden_head = hidden_head;
  p.cell_tail = cell_tail; p.hidden_tail = hidden_tail;
  p.beh = (const float*)d_in[10]; p.bet = (const float*)d_in[13];
  p.bh  = (const float*)d_in[16]; p.bt  = (const float*)d_in[21];
  p.bdh = (const float*)d_in[18]; p.bdt = (const float*)d_in[23];
  p.Wsrc[0] = (const float*)d_in[8];   // Weh1
  p.Wsrc[1] = (const float*)d_in[9];   // Weh2
  p.Wsrc[2] = (const float*)d_in[11];  // Wet1
  p.Wsrc[3] = (const float*)d_in[12];  // Wet2
  p.Wsrc[4] = (const float*)d_in[17];  // Wdh
  p.Wsrc[5] = (const float*)d_in[22];  // Wdt
  p.Wsrc[6] = (const float*)d_in[24];  // Wc1
  p.Wsrc[7] = (const float*)d_in[25];  // Wc2
  p.Wsrc[8] = (const float*)d_in[14];  // Wxh
  p.Wsrc[9] = (const float*)d_in[15];  // Whh
  p.Wsrc[10] = (const float*)d_in[19]; // Wxt
  p.Wsrc[11] = (const float*)d_in[20]; // Wht

  for (int m = 0; m < 12; ++m) {
    size_t n = (m < 8) ? 16384 : 65536;
    p.Wt[m] = (float*)(ws + off); off += n * 4;
  }

  p.out = (float*)d_out; p.rt = rt;
  p.order = order; p.level_off = level_off; p.n_levels = n_levels;
  p.ph = ph; p.pt = pt;
  p.S = S;

  hipMemsetAsync(rt, 0, (size_t)N * 4, stream);

  void* args[] = { (void*)&p };

  int dev = 0; hipGetDevice(&dev);
  int nCU = 0;
  hipDeviceGetAttribute(&nCU, hipDeviceAttributeMultiprocessorCount, dev);
  if (nCU <= 0) nCU = 256;
  int maxBlkPerCU = 0;
  if (hipOccupancyMaxActiveBlocksPerMultiprocessor(&maxBlkPerCU, process_kernel, TPB, 0)
      != hipSuccess || maxBlkPerCU < 1)
    maxBlkPerCU = 1;
  long long cap = (long long)nCU * (long long)maxBlkPerCU;
  int grid = (int)(cap < NBLK_MAX ? cap : NBLK_MAX);
  if (grid < 1) grid = nCU;

  hipError_t err = hipLaunchCooperativeKernel(process_kernel, dim3(grid), dim3(TPB),
                                              args, 0, stream);
  if (err != hipSuccess && grid > 128) {
    err = hipLaunchCooperativeKernel(process_kernel, dim3(128), dim3(TPB), args, 0, stream);
    grid = 128;
  }
  if (err != hipSuccess && grid > 64) {
    err = hipLaunchCooperativeKernel(process_kernel, dim3(64), dim3(TPB), args, 0, stream);
  }
}

// Round 10
// 790.285 us; speedup vs baseline: 1.0475x; 1.0475x over previous
//
#include <hip/hip_runtime.h>
#include <hip/hip_cooperative_groups.h>
#include <math.h>

namespace cg = cooperative_groups;

#define DD 128
#define G 16
#define TPB 512
#define SMAX 2048
#define NBLK_MAX 256

__device__ __forceinline__ float sigmoidf(float x) { return 1.0f / (1.0f + expf(-x)); }

// ---------------------------------------------------------------------------
// R15 = R14 with macro bug fixed (FMA44_1's parameter was named `w`, so the
// preprocessor rewrote the member access `.w` into `.wd` -> compile error).
// R14 design: 4x4 register-tiled GEMM phases.
// Diagnosis (R5..R13 all 447-590us, VALUBusy 3-5% regardless of G, stagger,
// pipelining): per-CU LDS *instruction issue* is the invariant bottleneck.
// Old structure: 4 FMAs per ds_read_b128 (row-broadcast reads), ~29K LDS
// instrs/CU/job ~= 70-140us/job. New: each thread owns a 4e x 4g tile;
// per d-row: 1 ds_read_b128 per input plane + 1 coalesced float4 weight load
// (row-major W, transpose preamble DELETED) -> 16 FMAs per LDS instr, ~4x
// fewer LDS instructions. Phase D keeps in-half rotation (R12 lesson).
// ---------------------------------------------------------------------------
struct PParams {
  const int* heads; const int* tails; const float* times;
  float* node_rep; float* cell_head; float* hidden_head; float* cell_tail; float* hidden_tail;
  const float* beh; const float* bet; const float* bh; const float* bt;
  const float* bdh; const float* bdt;
  const float* Weh1; const float* Weh2; const float* Wet1; const float* Wet2;
  const float* Wdh; const float* Wdt; const float* Wc1; const float* Wc2;
  const float* Wxh; const float* Whh; const float* Wxt; const float* Wht;
  float* out; float* rt;
  int* order; int* level_off; int* n_levels; int* ph; int* pt;
  int S;
};

// acc[4][4] += w1[i] * xa[j] + w2[i] * xb[j]
#define FMA44_2(A,w1,w2,xa,xb) { \
  A[0][0]+=(w1).x*(xa).x+(w2).x*(xb).x; A[0][1]+=(w1).x*(xa).y+(w2).x*(xb).y; \
  A[0][2]+=(w1).x*(xa).z+(w2).x*(xb).z; A[0][3]+=(w1).x*(xa).w+(w2).x*(xb).w; \
  A[1][0]+=(w1).y*(xa).x+(w2).y*(xb).x; A[1][1]+=(w1).y*(xa).y+(w2).y*(xb).y; \
  A[1][2]+=(w1).y*(xa).z+(w2).y*(xb).z; A[1][3]+=(w1).y*(xa).w+(w2).y*(xb).w; \
  A[2][0]+=(w1).z*(xa).x+(w2).z*(xb).x; A[2][1]+=(w1).z*(xa).y+(w2).z*(xb).y; \
  A[2][2]+=(w1).z*(xa).z+(w2).z*(xb).z; A[2][3]+=(w1).z*(xa).w+(w2).z*(xb).w; \
  A[3][0]+=(w1).w*(xa).x+(w2).w*(xb).x; A[3][1]+=(w1).w*(xa).y+(w2).w*(xb).y; \
  A[3][2]+=(w1).w*(xa).z+(w2).w*(xb).z; A[3][3]+=(w1).w*(xa).w+(w2).w*(xb).w; }

// acc[4][4] += wv_[i] * xa_[j]   (param renamed: `w` collided with `.w`)
#define FMA44_1(A,wv_,xa_) { \
  A[0][0]+=(wv_).x*(xa_).x; A[0][1]+=(wv_).x*(xa_).y; A[0][2]+=(wv_).x*(xa_).z; A[0][3]+=(wv_).x*(xa_).w; \
  A[1][0]+=(wv_).y*(xa_).x; A[1][1]+=(wv_).y*(xa_).y; A[1][2]+=(wv_).y*(xa_).z; A[1][3]+=(wv_).y*(xa_).w; \
  A[2][0]+=(wv_).z*(xa_).x; A[2][1]+=(wv_).z*(xa_).y; A[2][2]+=(wv_).z*(xa_).z; A[2][3]+=(wv_).z*(xa_).w; \
  A[3][0]+=(wv_).w*(xa_).x; A[3][1]+=(wv_).w*(xa_).y; A[3][2]+=(wv_).w*(xa_).z; A[3][3]+=(wv_).w*(xa_).w; }

__global__ __launch_bounds__(TPB, 2) void process_kernel(PParams p) {
  cg::grid_group grid = cg::this_grid();
  const int tid = threadIdx.x;
  const int bid = (int)blockIdx.x;
  const int nb  = (int)gridDim.x;
  const int Sn  = p.S;
  const int wv  = tid >> 6;
  const int d0  = ((bid * 8 + wv) * 37) & 127;   // per-wave d rotation

  __shared__ __align__(16) float S_[32768];   // 128 KB
  __shared__ int sIdx[G], hIdx[G], tIdx[G];
  __shared__ float tmv[G], decHs[G], decTs[G];
  __shared__ int sh_changed, sh_maxl;

  // plane offsets (floats), stride 16 per d-row
  const int O_REPH = 0,     O_REPT = 2048,  O_CHS = 4096,  O_CTS = 6144;  // dead after A
  const int O_ZH   = 0,     O_ZT   = 8192;                                 // born in B (overlay)
  const int O_HHS  = 16384, O_HTS  = 18432, O_HTH = 20480, O_HHT = 22528;  // persistent
  const int O_EH   = 24576, O_ET   = 26624;                                // edge (A..B) == nh (C..D)
  const int O_CAH  = 28672, O_CAT  = 30720;                                // cadj (A..C), D-partial scratch

  // ---- pred: wave-per-j
  {
    const int lane = tid & 63;
    for (int j = bid * 8 + wv; j < Sn; j += nb * 8) {
      const int myh = p.heads[j], myt = p.tails[j];
      int mph = -1, mpt = -1;
      for (int i = lane; i < j; i += 64) {
        int a = p.heads[i], b = p.tails[i];
        if (a == myh || b == myh) mph = i;
        if (a == myt || b == myt) mpt = i;
      }
#pragma unroll
      for (int off = 32; off > 0; off >>= 1) {
        mph = max(mph, __shfl_down(mph, off));
        mpt = max(mpt, __shfl_down(mpt, off));
      }
      if (lane == 0) { p.ph[j] = mph; p.pt[j] = mpt; }
    }
  }
  __threadfence();
  grid.sync();

  // ---- level finalize (block 0; S_ as int scratch)
  if (bid == 0) {
    int* lvl = (int*)S_;
    int* ph2 = lvl + SMAX;
    int* pt2 = ph2 + SMAX;
    int* cnt = pt2 + SMAX;
    for (int j = tid; j < Sn; j += TPB) { ph2[j] = p.ph[j]; pt2[j] = p.pt[j]; lvl[j] = 1; }
    __syncthreads();
    for (int it = 0; it < Sn + 2; ++it) {
      if (tid == 0) sh_changed = 0;
      __syncthreads();
      for (int j = tid; j < Sn; j += TPB) {
        int l = 1;
        int a = ph2[j]; if (a >= 0) l = lvl[a] + 1;
        int b = pt2[j]; if (b >= 0) { int lb = lvl[b] + 1; if (lb > l) l = lb; }
        if (l != lvl[j]) { lvl[j] = l; sh_changed = 1; }
      }
      __syncthreads();
      if (!sh_changed) break;
      __syncthreads();
    }
    if (tid == 0) sh_maxl = 0;
    __syncthreads();
    for (int j = tid; j < Sn; j += TPB) atomicMax(&sh_maxl, lvl[j]);
    __syncthreads();
    const int Mlvl = sh_maxl;
    for (int l = tid; l < Mlvl; l += TPB) cnt[l] = 0;
    __syncthreads();
    for (int j = tid; j < Sn; j += TPB) atomicAdd(&cnt[lvl[j] - 1], 1);
    __syncthreads();
    if (tid == 0) {
      int run = 0; p.level_off[0] = 0;
      for (int l = 0; l < Mlvl; ++l) { run += cnt[l]; p.level_off[l + 1] = run; }
      p.n_levels[0] = Mlvl;
    }
    __syncthreads();
    for (int l = tid; l < Mlvl; l += TPB) cnt[l] = 0;
    __syncthreads();
    for (int j = tid; j < Sn; j += TPB) {
      int lv2 = lvl[j] - 1;
      int pos = p.level_off[lv2] + atomicAdd(&cnt[lv2], 1);
      p.order[pos] = j;
    }
  }
  __threadfence();
  grid.sync();

  int nlv = p.n_levels[0];
  if (nlv < 0) nlv = 0;
  if (nlv > SMAX) nlv = SMAX;

  for (int lv = 0; lv < nlv; ++lv) {
    const int beg = p.level_off[lv], end = p.level_off[lv + 1];

    for (int base = beg + bid * G; base < end; base += nb * G) {
      const int ng = min(G, end - base);
      __syncthreads();
      if (tid < ng) {
        int s = p.order[base + tid]; sIdx[tid] = s;
        int h = p.heads[s], t = p.tails[s];
        hIdx[tid] = h; tIdx[tid] = t;
        float tm = p.times[s]; tmv[tid] = tm;
        decHs[tid] = expf(-(tm - p.rt[h]));
        decTs[tid] = expf(-(tm - p.rt[t]));
      }
      __syncthreads();

      // -------- Gather: node rows into [d][16] LDS + emit outputs
      {
        const int d = tid & 127;
        for (int g = tid >> 7; g < ng; g += 4) {
          const size_t oh = (size_t)hIdx[g] * DD + d;
          const size_t ot = (size_t)tIdx[g] * DD + d;
          const int b = d * 16 + g;
          float rh = p.node_rep[oh];
          S_[O_REPH + b] = rh; p.out[(size_t)sIdx[g] * DD + d] = rh;
          S_[O_CHS + b] = p.cell_head[oh];
          S_[O_HHS + b] = p.hidden_head[oh];
          S_[O_HTH + b] = p.hidden_tail[oh];
          float rt_ = p.node_rep[ot];
          S_[O_REPT + b] = rt_; p.out[(size_t)(Sn + sIdx[g]) * DD + d] = rt_;
          S_[O_CTS + b] = p.cell_tail[ot];
          S_[O_HTS + b] = p.hidden_tail[ot];
          S_[O_HHT + b] = p.hidden_head[ot];
        }
      }
      __syncthreads();

      // -------- Phase A: edges (roles 0,1) + decayed cell adjust (roles 2,3)
      {
        const int role = tid >> 7;
        const int r = tid & 127;
        const int e0 = (r >> 2) * 4;
        const int g0 = (r & 3) * 4;
        if (role <= 1) {
          const float* W1 = role ? p.Wet1 : p.Weh1;
          const float* W2 = role ? p.Wet2 : p.Weh2;
          const float* bias = role ? p.bet : p.beh;
          float acc[4][4];
#pragma unroll
          for (int i = 0; i < 4; ++i) {
            float bv = bias[e0 + i];
            acc[i][0] = bv; acc[i][1] = bv; acc[i][2] = bv; acc[i][3] = bv;
          }
#pragma unroll 4
          for (int i = 0; i < 128; ++i) {
            const int d = (i + d0) & 127;
            float4 w1 = *(const float4*)&W1[d * 128 + e0];
            float4 w2 = *(const float4*)&W2[d * 128 + e0];
            float4 xh = *(const float4*)&S_[O_REPH + d * 16 + g0];
            float4 xt = *(const float4*)&S_[O_REPT + d * 16 + g0];
            FMA44_2(acc, w1, w2, xh, xt);
          }
          const int dst = role ? O_ET : O_EH;
#pragma unroll
          for (int i = 0; i < 4; ++i)
            *(float4*)&S_[dst + (e0 + i) * 16 + g0] =
                make_float4(tanhf(acc[i][0]), tanhf(acc[i][1]),
                            tanhf(acc[i][2]), tanhf(acc[i][3]));
        } else {
          const int th = (role == 2);
          const float* W = th ? p.Wdh : p.Wdt;
          const float* bias = th ? p.bdh : p.bdt;
          const int co = th ? O_CHS : O_CTS;
          const float* decA = th ? decHs : decTs;
          float acc[4][4];
#pragma unroll
          for (int i = 0; i < 4; ++i) {
            float bv = bias[e0 + i];
            acc[i][0] = bv; acc[i][1] = bv; acc[i][2] = bv; acc[i][3] = bv;
          }
#pragma unroll 4
          for (int i = 0; i < 128; ++i) {
            const int d = (i + d0) & 127;
            float4 wdv = *(const float4*)&W[d * 128 + e0];
            float4 cv = *(const float4*)&S_[co + d * 16 + g0];
            FMA44_1(acc, wdv, cv);
          }
          const float dv0 = decA[g0], dv1 = decA[g0 + 1],
                      dv2 = decA[g0 + 2], dv3 = decA[g0 + 3];
          const int dst = th ? O_CAH : O_CAT;
#pragma unroll
          for (int i = 0; i < 4; ++i) {
            float4 cv = *(const float4*)&S_[co + (e0 + i) * 16 + g0];
            float cs0 = tanhf(acc[i][0]), cs1 = tanhf(acc[i][1]);
            float cs2 = tanhf(acc[i][2]), cs3 = tanhf(acc[i][3]);
            *(float4*)&S_[dst + (e0 + i) * 16 + g0] =
                make_float4(cv.x - cs0 + cs0 * dv0, cv.y - cs1 + cs1 * dv1,
                            cv.z - cs2 + cs2 * dv2, cv.w - cs3 + cs3 * dv3);
          }
        }
      }
      __syncthreads();

      // -------- Phase B: z = x@Wx + h@Wh + b, 4c x 4g x both sides per thread
      {
        const int c0 = (tid >> 2) * 4;
        const int g0 = (tid & 3) * 4;
        float ah[4][4], at[4][4];
#pragma unroll
        for (int i = 0; i < 4; ++i) {
          float bhv = p.bh[c0 + i], btv = p.bt[c0 + i];
          ah[i][0] = bhv; ah[i][1] = bhv; ah[i][2] = bhv; ah[i][3] = bhv;
          at[i][0] = btv; at[i][1] = btv; at[i][2] = btv; at[i][3] = btv;
        }
#pragma unroll 2
        for (int i = 0; i < 128; ++i) {
          const int d = (i + d0) & 127;
          float4 wxh = *(const float4*)&p.Wxh[d * 512 + c0];
          float4 whh = *(const float4*)&p.Whh[d * 512 + c0];
          float4 wxt = *(const float4*)&p.Wxt[d * 512 + c0];
          float4 wht = *(const float4*)&p.Wht[d * 512 + c0];
          float4 xe = *(const float4*)&S_[O_EH  + d * 16 + g0];
          float4 xh = *(const float4*)&S_[O_HHS + d * 16 + g0];
          float4 fe = *(const float4*)&S_[O_ET  + d * 16 + g0];
          float4 fh = *(const float4*)&S_[O_HTS + d * 16 + g0];
          FMA44_2(ah, wxh, whh, xe, xh);
          FMA44_2(at, wxt, wht, fe, fh);
        }
#pragma unroll
        for (int i = 0; i < 4; ++i) {
          *(float4*)&S_[O_ZH + (c0 + i) * 16 + g0] =
              make_float4(ah[i][0], ah[i][1], ah[i][2], ah[i][3]);
          *(float4*)&S_[O_ZT + (c0 + i) * 16 + g0] =
              make_float4(at[i][0], at[i][1], at[i][2], at[i][3]);
        }
      }
      __syncthreads();

      // -------- Phase C: gates, c/h update, scatter state, rt update
      {
        const int side = tid >> 8, sub = (tid >> 7) & 1, e2 = tid & 127;
        const int zo = side ? O_ZT : O_ZH;
        const int co = side ? O_CAT : O_CAH;
        const int no = side ? O_ET : O_EH;
        float* ctab = side ? p.cell_tail : p.cell_head;
        float* htab = side ? p.hidden_tail : p.hidden_head;
        for (int q = 0; q < 8; ++q) {
          int g = sub + 2 * q;
          if (g >= ng) continue;
          float iv = sigmoidf(S_[zo + e2 * 16 + g]);
          float fv = sigmoidf(S_[zo + (128 + e2) * 16 + g]);
          float ov = sigmoidf(S_[zo + (256 + e2) * 16 + g]);
          float gv = tanhf(S_[zo + (384 + e2) * 16 + g]);
          float cadj = S_[co + e2 * 16 + g];
          float cn = fv * cadj + iv * gv;
          float hn = ov * tanhf(cn);
          S_[no + e2 * 16 + g] = hn;
          int node = side ? tIdx[g] : hIdx[g];
          ctab[(size_t)node * DD + e2] = cn;
          htab[(size_t)node * DD + e2] = hn;
        }
        if (tid < 2 * G) {
          int g = tid & (G - 1);
          if (g < ng) p.rt[(tid >= G) ? tIdx[g] : hIdx[g]] = tmv[g];
        }
      }
      __syncthreads();

      // -------- Phase D: combiner, 4x4 tiles, d-halves + LDS partial combine
      {
        const int role = tid >> 8;          // 0: head output, 1: tail output
        const int dh = (tid >> 7) & 1;      // d-half
        const int r = tid & 127;
        const int e0 = (r >> 2) * 4;
        const int g0 = (r & 3) * 4;
        const int xo = role ? O_HHT : O_EH;   // @ Wc1
        const int yo = role ? O_ET  : O_HTH;  // @ Wc2
        const int s0 = dh * 64;
        float acc[4][4];
#pragma unroll
        for (int i = 0; i < 4; ++i) {
          acc[i][0] = 0.f; acc[i][1] = 0.f; acc[i][2] = 0.f; acc[i][3] = 0.f;
        }
#pragma unroll 4
        for (int i = 0; i < 64; ++i) {
          const int d = s0 + ((i + d0) & 63);   // rotation stays inside the half
          float4 w1 = *(const float4*)&p.Wc1[d * 128 + e0];
          float4 w2 = *(const float4*)&p.Wc2[d * 128 + e0];
          float4 xv = *(const float4*)&S_[xo + d * 16 + g0];
          float4 yv = *(const float4*)&S_[yo + d * 16 + g0];
          FMA44_2(acc, w1, w2, xv, yv);
        }
        const int scr = role ? O_CAT : O_CAH;   // cadj dead after Phase C
        if (dh == 1) {
#pragma unroll
          for (int i = 0; i < 4; ++i)
            *(float4*)&S_[scr + (e0 + i) * 16 + g0] =
                make_float4(acc[i][0], acc[i][1], acc[i][2], acc[i][3]);
        }
        __syncthreads();
        if (dh == 0) {
#pragma unroll
          for (int i = 0; i < 4; ++i) {
            float4 pv = *(const float4*)&S_[scr + (e0 + i) * 16 + g0];
            acc[i][0] += pv.x; acc[i][1] += pv.y; acc[i][2] += pv.z; acc[i][3] += pv.w;
          }
#pragma unroll
          for (int j = 0; j < 4; ++j) {
            int g = g0 + j;
            if (g < ng) {
              if (role == 0) {
                if (hIdx[g] != tIdx[g]) {
                  size_t nbase = (size_t)hIdx[g] * DD;
#pragma unroll
                  for (int i = 0; i < 4; ++i)
                    p.node_rep[nbase + e0 + i] = tanhf(acc[i][j]);
                }
              } else {
                size_t nbase = (size_t)tIdx[g] * DD;
#pragma unroll
                for (int i = 0; i < 4; ++i)
                  p.node_rep[nbase + e0 + i] = tanhf(acc[i][j]);
              }
            }
          }
        }
      }
    }
    __threadfence();
    grid.sync();
  }
}

// ---------------------------------------------------------------------------
extern "C" void kernel_launch(void* const* d_in, const int* in_sizes, int n_in,
                              void* d_out, int out_size, void* d_ws, size_t ws_size,
                              hipStream_t stream) {
  const int* heads = (const int*)d_in[0];
  const int* tails = (const int*)d_in[1];
  const float* times = (const float*)d_in[2];
  float* node_rep    = (float*)d_in[3];
  float* cell_head   = (float*)d_in[4];
  float* hidden_head = (float*)d_in[5];
  float* cell_tail   = (float*)d_in[6];
  float* hidden_tail = (float*)d_in[7];

  const int S = in_sizes[0];
  const int N = in_sizes[3] / DD;

  char* ws = (char*)d_ws;
  size_t off = 0;
  float* rt = (float*)ws;
  off = (((size_t)N * 4) + 511) & ~(size_t)511;
  int* order     = (int*)(ws + off); off += (size_t)SMAX * 4;
  int* level_off = (int*)(ws + off); off += (size_t)(SMAX + 1) * 4;
  int* n_levels  = (int*)(ws + off); off += 64 * 4;
  int* ph        = (int*)(ws + off); off += (size_t)SMAX * 4;
  int* pt        = (int*)(ws + off); off += (size_t)SMAX * 4;

  PParams p;
  p.heads = heads; p.tails = tails; p.times = times;
  p.node_rep = node_rep; p.cell_head = cell_head; p.hidden_head = hidden_head;
  p.cell_tail = cell_tail; p.hidden_tail = hidden_tail;
  p.beh = (const float*)d_in[10]; p.bet = (const float*)d_in[13];
  p.bh  = (const float*)d_in[16]; p.bt  = (const float*)d_in[21];
  p.bdh = (const float*)d_in[18]; p.bdt = (const float*)d_in[23];
  p.Weh1 = (const float*)d_in[8];
  p.Weh2 = (const float*)d_in[9];
  p.Wet1 = (const float*)d_in[11];
  p.Wet2 = (const float*)d_in[12];
  p.Wxh  = (const float*)d_in[14];
  p.Whh  = (const float*)d_in[15];
  p.Wdh  = (const float*)d_in[17];
  p.Wxt  = (const float*)d_in[19];
  p.Wht  = (const float*)d_in[20];
  p.Wdt  = (const float*)d_in[22];
  p.Wc1  = (const float*)d_in[24];
  p.Wc2  = (const float*)d_in[25];

  p.out = (float*)d_out; p.rt = rt;
  p.order = order; p.level_off = level_off; p.n_levels = n_levels;
  p.ph = ph; p.pt = pt;
  p.S = S;

  hipMemsetAsync(rt, 0, (size_t)N * 4, stream);

  void* args[] = { (void*)&p };

  int dev = 0; hipGetDevice(&dev);
  int nCU = 0;
  hipDeviceGetAttribute(&nCU, hipDeviceAttributeMultiprocessorCount, dev);
  if (nCU <= 0) nCU = 256;
  int maxBlkPerCU = 0;
  if (hipOccupancyMaxActiveBlocksPerMultiprocessor(&maxBlkPerCU, process_kernel, TPB, 0)
      != hipSuccess || maxBlkPerCU < 1)
    maxBlkPerCU = 1;
  long long cap = (long long)nCU * (long long)maxBlkPerCU;
  int grid = (int)(cap < NBLK_MAX ? cap : NBLK_MAX);
  if (grid < 1) grid = nCU;

  hipError_t err = hipLaunchCooperativeKernel(process_kernel, dim3(grid), dim3(TPB),
                                              args, 0, stream);
  if (err != hipSuccess && grid > 128) {
    err = hipLaunchCooperativeKernel(process_kernel, dim3(128), dim3(TPB), args, 0, stream);
    grid = 128;
  }
  if (err != hipSuccess && grid > 64) {
    err = hipLaunchCooperativeKernel(process_kernel, dim3(64), dim3(TPB), args, 0, stream);
  }
}